// Round 6
// baseline (486.299 us; speedup 1.0000x reference)
//
#include <hip/hip_runtime.h>
#include <hip/hip_bf16.h>
#include <math.h>

// DenseGCN3Layer on MI355X — round 6.
// Changes vs r5:
//  * All MFMA GEMMs barrier-free and LDS-free: A-frags loaded from global
//    (L1-coalesced 16-row x 32B segments, 4x intra-block reuse via L1),
//    in-register fp32->bf16 convert, B-frags from global (L2-hot Wt).
//    Fully unrolled K loops, zero __syncthreads.
//  * gemm_mfma0 tile 128->64 rows (grid 782 -> 1563) for occupancy.
//  * agg unroll deepened: U = 8/4/2 for F = 64/32/16.

#define NBUCK_MAX 512
#define P1_CHUNK 8192
#define EPT 32
#define BCAP 9216

typedef __attribute__((ext_vector_type(8))) short bfrag;   // 8 bf16 (4 VGPR)
typedef __attribute__((ext_vector_type(4))) float f4_t;    // acc

__device__ inline float uaf(unsigned u) { return __uint_as_float(u); }
__device__ inline ushort f2bf(float f) {
    __hip_bfloat16 b = __float2bfloat16(f);
    return *reinterpret_cast<ushort*>(&b);
}
__device__ inline bfrag cvt8(const float4 a, const float4 b) {
    union { ushort u[8]; bfrag f; } r;
    r.u[0] = f2bf(a.x); r.u[1] = f2bf(a.y); r.u[2] = f2bf(a.z); r.u[3] = f2bf(a.w);
    r.u[4] = f2bf(b.x); r.u[5] = f2bf(b.y); r.u[6] = f2bf(b.z); r.u[7] = f2bf(b.w);
    return r.f;
}
__device__ inline bfrag ld_bfrag(const ushort* p) {
    const uint4 raw = *reinterpret_cast<const uint4*>(p);
    return *reinterpret_cast<const bfrag*>(&raw);
}

// ---------------------------------------------------------------- build (r3)

__global__ __launch_bounds__(256) void bucket_hist_kernel(
    const int* __restrict__ dst, int E, int* __restrict__ bucket_count, int nbuckets)
{
    __shared__ int lhist[NBUCK_MAX];
    for (int i = threadIdx.x; i < nbuckets; i += 256) lhist[i] = 0;
    __syncthreads();
    const int stride = gridDim.x * 256;
    for (int e = blockIdx.x * 256 + threadIdx.x; e < E; e += stride)
        atomicAdd(&lhist[dst[e] >> 8], 1);
    __syncthreads();
    for (int i = threadIdx.x; i < nbuckets; i += 256) {
        int c = lhist[i];
        if (c) atomicAdd(&bucket_count[i], c);
    }
}

__global__ __launch_bounds__(512) void bucket_scan_kernel(
    const int* __restrict__ bucket_count, int* __restrict__ bucket_base,
    int* __restrict__ bucket_cursor, int nbuckets)
{
    __shared__ int tmp[512];
    const int tid = threadIdx.x;
    int v = (tid < nbuckets) ? bucket_count[tid] : 0;
    tmp[tid] = v;
    __syncthreads();
    for (int off = 1; off < 512; off <<= 1) {
        int t = (tid >= off) ? tmp[tid - off] : 0;
        __syncthreads();
        tmp[tid] += t;
        __syncthreads();
    }
    if (tid < nbuckets) {
        int base = tmp[tid] - v;
        bucket_base[tid]   = base;
        bucket_cursor[tid] = base;
    }
}

__global__ __launch_bounds__(256) void partition_kernel(
    const int* __restrict__ src, const int* __restrict__ dst, int E,
    int* __restrict__ bucket_cursor, unsigned int* __restrict__ keys, int nbuckets)
{
    __shared__ int hist[NBUCK_MAX];
    __shared__ int lofs[NBUCK_MAX];
    __shared__ int gbase[NBUCK_MAX];
    __shared__ int lcur[NBUCK_MAX];
    __shared__ int ssum[256];
    __shared__ unsigned int stage[P1_CHUNK];
    __shared__ int gidx[P1_CHUNK];

    const int tid = threadIdx.x;
    const int e0  = blockIdx.x * P1_CHUNK;
    const int nE  = min(P1_CHUNK, E - e0);

    for (int i = tid; i < NBUCK_MAX; i += 256) { hist[i] = 0; lcur[i] = 0; }
    __syncthreads();

    int myb[EPT];
    unsigned int mypk[EPT];
#pragma unroll
    for (int j = 0; j < EPT; ++j) {
        const int e = e0 + tid + j * 256;
        if (e < E) {
            const int d = dst[e];
            myb[j]  = d >> 8;
            mypk[j] = ((unsigned int)(d & 255) << 17) | (unsigned int)src[e];
            atomicAdd(&hist[myb[j]], 1);
        } else myb[j] = -1;
    }
    __syncthreads();

    int a0 = (2 * tid     < nbuckets) ? hist[2 * tid]     : 0;
    int a1 = (2 * tid + 1 < nbuckets) ? hist[2 * tid + 1] : 0;
    ssum[tid] = a0 + a1;
    __syncthreads();
    for (int off = 1; off < 256; off <<= 1) {
        int t = (tid >= off) ? ssum[tid - off] : 0;
        __syncthreads();
        ssum[tid] += t;
        __syncthreads();
    }
    const int ex = ssum[tid] - (a0 + a1);
    if (2 * tid     < nbuckets) lofs[2 * tid]     = ex;
    if (2 * tid + 1 < nbuckets) lofs[2 * tid + 1] = ex + a0;
    __syncthreads();

    for (int i = tid; i < nbuckets; i += 256)
        gbase[i] = atomicAdd(&bucket_cursor[i], hist[i]);
    __syncthreads();

#pragma unroll
    for (int j = 0; j < EPT; ++j) {
        if (myb[j] >= 0) {
            const int b = myb[j];
            const int l = lofs[b] + atomicAdd(&lcur[b], 1);
            stage[l] = mypk[j];
            gidx[l]  = gbase[b] - lofs[b] + l;
        }
    }
    __syncthreads();

    for (int i = tid; i < nE; i += 256)
        keys[gidx[i]] = stage[i];
}

__global__ __launch_bounds__(256) void csr_build_kernel(
    const unsigned int* __restrict__ keys, const int* __restrict__ bucket_base,
    const int* __restrict__ bucket_count,
    int* __restrict__ row_off, float* __restrict__ dinv, int* __restrict__ col,
    int N, int E)
{
    __shared__ unsigned int inb[BCAP];
    __shared__ int outv[BCAP];
    __shared__ int hist[256];
    __shared__ int lofs[256];
    __shared__ int ssum[256];

    const int tid  = threadIdx.x;
    const int b    = blockIdx.x;
    const int base = bucket_base[b];
    const int cnt  = min(bucket_count[b], BCAP);
    const int n0   = b << 8;
    const int nn   = min(256, N - n0);

    for (int i = tid; i < cnt; i += 256) inb[i] = keys[base + i];
    hist[tid] = 0;
    __syncthreads();

    for (int i = tid; i < cnt; i += 256)
        atomicAdd(&hist[inb[i] >> 17], 1);
    __syncthreads();

    ssum[tid] = hist[tid];
    __syncthreads();
    for (int off = 1; off < 256; off <<= 1) {
        int t = (tid >= off) ? ssum[tid - off] : 0;
        __syncthreads();
        ssum[tid] += t;
        __syncthreads();
    }
    lofs[tid] = ssum[tid] - hist[tid];

    if (tid < nn) {
        row_off[n0 + tid] = base + lofs[tid];
        dinv[n0 + tid]    = rsqrtf((float)hist[tid] + 1.0f);
    }
    if (b == 0 && tid == 0) row_off[N] = E;
    __syncthreads();

    hist[tid] = 0;
    __syncthreads();

    for (int i = tid; i < cnt; i += 256) {
        const unsigned int k = inb[i];
        const int node = k >> 17;
        const int l = lofs[node] + atomicAdd(&hist[node], 1);
        outv[l] = (int)(k & 0x1FFFF);
    }
    __syncthreads();

    for (int i = tid; i < cnt; i += 256)
        col[base + i] = outv[i];
}

// ---------------------------------------------------------------- weight prep

__global__ __launch_bounds__(256) void prep_weights_kernel(
    const float* __restrict__ W1, const float* __restrict__ Ws02,
    const float* __restrict__ Ws03, const float* __restrict__ W2,
    const float* __restrict__ Ws13, const float* __restrict__ W3,
    ushort* __restrict__ Wt0, ushort* __restrict__ Wt1, ushort* __restrict__ Wt2)
{
    int idx = blockIdx.x * 256 + threadIdx.x;
    if (idx < 32768) {
        int f = idx >> 8, k = idx & 255;
        float v = 0.f;
        if (f < 64)       v = W1[k * 64 + f];
        else if (f < 96)  v = Ws02[k * 32 + (f - 64)];
        else if (f < 112) v = Ws03[k * 16 + (f - 96)];
        Wt0[idx] = f2bf(v);
    } else if (idx < 32768 + 3072) {
        int t = idx - 32768;
        int f = t >> 6, k = t & 63;
        float v = (f < 32) ? W2[k * 32 + f] : Ws13[k * 16 + (f - 32)];
        Wt1[t] = f2bf(v);
    } else if (idx < 32768 + 3072 + 512) {
        int t = idx - 32768 - 3072;
        int f = t >> 5, k = t & 31;
        Wt2[t] = f2bf(W3[k * 16 + f]);
    }
}

// ---------------------------------------------------------------- MFMA GEMMs
// Barrier-free, LDS-free. A-frag: A[m=lane&15][k=(lane>>4)*8+j];
// B-frag: B[n=lane&15][k=...]; C/D: col(f)=lane&15, row(n)=(lane>>4)*4+reg.

// MODE 0: x[N,256] fp32 @ Wt0[128][256] -> g1(bf16), pre2, pre3.
// Block = 64 rows, 4 waves; wave wf covers f-slice [wf*32, wf*32+32).
__global__ __launch_bounds__(256, 4) void gemm_mfma0(
    const float* __restrict__ X, const ushort* __restrict__ Wt0,
    const float* __restrict__ bs02, const float* __restrict__ bs03,
    const float* __restrict__ dinv,
    __hip_bfloat16* __restrict__ g1, float* __restrict__ pre2,
    float* __restrict__ pre3, int N)
{
    const int tid  = threadIdx.x;
    const int lane = tid & 63;
    const int wf   = tid >> 6;          // f-slice
    const int n0   = blockIdx.x * 64;
    const int mrow = lane & 15;
    const int kq   = (lane >> 4) * 8;   // k offset within panel (elems)

    f4_t acc[4][2];
#pragma unroll
    for (int a = 0; a < 4; ++a)
#pragma unroll
        for (int b = 0; b < 2; ++b) acc[a][b] = {0.f, 0.f, 0.f, 0.f};

    // clamped row pointers (rows >= N read row N-1; their results are never stored)
    const float* xrow[4];
#pragma unroll
    for (int mt = 0; mt < 4; ++mt) {
        int r = n0 + mt * 16 + mrow;
        r = (r < N) ? r : (N - 1);
        xrow[mt] = &X[(size_t)r * 256 + kq];
    }
    const ushort* wrow[2];
#pragma unroll
    for (int ft = 0; ft < 2; ++ft)
        wrow[ft] = &Wt0[(size_t)(wf * 32 + ft * 16 + mrow) * 256 + kq];

#pragma unroll
    for (int p = 0; p < 8; ++p) {
        bfrag bf[2];
#pragma unroll
        for (int ft = 0; ft < 2; ++ft)
            bf[ft] = ld_bfrag(&wrow[ft][p * 32]);
        bfrag af[4];
#pragma unroll
        for (int mt = 0; mt < 4; ++mt) {
            const float4 u0 = *reinterpret_cast<const float4*>(&xrow[mt][p * 32]);
            const float4 u1 = *reinterpret_cast<const float4*>(&xrow[mt][p * 32 + 4]);
            af[mt] = cvt8(u0, u1);
        }
#pragma unroll
        for (int mt = 0; mt < 4; ++mt)
#pragma unroll
            for (int ft = 0; ft < 2; ++ft)
                acc[mt][ft] = __builtin_amdgcn_mfma_f32_16x16x32_bf16(
                    af[mt], bf[ft], acc[mt][ft], 0, 0, 0);
    }

#pragma unroll
    for (int mt = 0; mt < 4; ++mt) {
#pragma unroll
        for (int ft = 0; ft < 2; ++ft) {
            const int fg = wf * 32 + ft * 16 + mrow;
#pragma unroll
            for (int r = 0; r < 4; ++r) {
                const int n = n0 + mt * 16 + (lane >> 4) * 4 + r;
                if (n >= N) continue;
                const float a = acc[mt][ft][r];
                if (fg < 64) {
                    g1[(size_t)n * 64 + fg] = __float2bfloat16(dinv[n] * a);
                } else if (fg < 96) {
                    pre2[(size_t)n * 32 + (fg - 64)] = a + bs02[fg - 64];
                } else if (fg < 112) {
                    pre3[(size_t)n * 16 + (fg - 96)] = a + bs03[fg - 96];
                }
            }
        }
    }
}

// MODE 1: x1[N,64] bf16 @ Wt1[48][64] -> g2(bf16), pre3 += (. + bs13).
// Block = 128 rows, 4 waves; wave w covers rows [w*32, w*32+32), all 48 f.
__global__ __launch_bounds__(256) void gemm_mfma1(
    const ushort* __restrict__ X1, const ushort* __restrict__ Wt1,
    const float* __restrict__ bs13, const float* __restrict__ dinv,
    __hip_bfloat16* __restrict__ g2, float* __restrict__ pre3, int N)
{
    const int tid  = threadIdx.x;
    const int lane = tid & 63;
    const int wave = tid >> 6;
    const int n0   = blockIdx.x * 128 + wave * 32;
    const int mrow = lane & 15;
    const int kq   = (lane >> 4) * 8;

    f4_t acc[2][3];
#pragma unroll
    for (int a = 0; a < 2; ++a)
#pragma unroll
        for (int b = 0; b < 3; ++b) acc[a][b] = {0.f, 0.f, 0.f, 0.f};

    const ushort* xrow[2];
#pragma unroll
    for (int mt = 0; mt < 2; ++mt) {
        int r = n0 + mt * 16 + mrow;
        r = (r < N) ? r : (N - 1);
        xrow[mt] = &X1[(size_t)r * 64 + kq];
    }
    const ushort* wrow[3];
#pragma unroll
    for (int ft = 0; ft < 3; ++ft)
        wrow[ft] = &Wt1[(size_t)(ft * 16 + mrow) * 64 + kq];

#pragma unroll
    for (int p = 0; p < 2; ++p) {
        bfrag af[2], bf[3];
#pragma unroll
        for (int mt = 0; mt < 2; ++mt) af[mt] = ld_bfrag(&xrow[mt][p * 32]);
#pragma unroll
        for (int ft = 0; ft < 3; ++ft) bf[ft] = ld_bfrag(&wrow[ft][p * 32]);
#pragma unroll
        for (int mt = 0; mt < 2; ++mt)
#pragma unroll
            for (int ft = 0; ft < 3; ++ft)
                acc[mt][ft] = __builtin_amdgcn_mfma_f32_16x16x32_bf16(
                    af[mt], bf[ft], acc[mt][ft], 0, 0, 0);
    }

#pragma unroll
    for (int mt = 0; mt < 2; ++mt) {
#pragma unroll
        for (int ft = 0; ft < 3; ++ft) {
            const int fg = ft * 16 + mrow;
#pragma unroll
            for (int r = 0; r < 4; ++r) {
                const int n = n0 + mt * 16 + (lane >> 4) * 4 + r;
                if (n >= N) continue;
                const float a = acc[mt][ft][r];
                if (fg < 32) {
                    g2[(size_t)n * 32 + fg] = __float2bfloat16(dinv[n] * a);
                } else {
                    pre3[(size_t)n * 16 + (fg - 32)] += a + bs13[fg - 32];
                }
            }
        }
    }
}

// MODE 2: x2[N,32] bf16 @ Wt2[16][32] -> g3(bf16).
// Block = 128 rows, 4 waves; wave w covers rows [w*32, w*32+32).
__global__ __launch_bounds__(256) void gemm_mfma2(
    const ushort* __restrict__ X2, const ushort* __restrict__ Wt2,
    const float* __restrict__ dinv, __hip_bfloat16* __restrict__ g3, int N)
{
    const int tid  = threadIdx.x;
    const int lane = tid & 63;
    const int wave = tid >> 6;
    const int n0   = blockIdx.x * 128 + wave * 32;
    const int mrow = lane & 15;
    const int kq   = (lane >> 4) * 8;

    f4_t acc[2];
#pragma unroll
    for (int a = 0; a < 2; ++a) acc[a] = {0.f, 0.f, 0.f, 0.f};

    const bfrag bf = ld_bfrag(&Wt2[(size_t)mrow * 32 + kq]);
#pragma unroll
    for (int mt = 0; mt < 2; ++mt) {
        int r = n0 + mt * 16 + mrow;
        r = (r < N) ? r : (N - 1);
        const bfrag af = ld_bfrag(&X2[(size_t)r * 32 + kq]);
        acc[mt] = __builtin_amdgcn_mfma_f32_16x16x32_bf16(af, bf, acc[mt], 0, 0, 0);
    }

#pragma unroll
    for (int mt = 0; mt < 2; ++mt) {
#pragma unroll
        for (int r = 0; r < 4; ++r) {
            const int n = n0 + mt * 16 + (lane >> 4) * 4 + r;
            if (n >= N) continue;
            g3[(size_t)n * 16 + mrow] = __float2bfloat16(dinv[n] * acc[mt][r]);
        }
    }
}

// ---------------------------------------------------------------- aggregation
// One wave/node, 4 feats per lane (uint2 = 4 bf16), FG=F/4 lanes per edge,
// EPW=64/FG edge slots, U-deep unroll (mean degree 32 -> one burst).

template<int F, int MODE>
__global__ __launch_bounds__(256) void agg_kernel(
    const ushort* __restrict__ g, const float* __restrict__ dinv,
    const int* __restrict__ row_off, const int* __restrict__ col,
    const float* __restrict__ bias, const float* __restrict__ pre,
    const float* __restrict__ Wout, const float* __restrict__ bout,
    void* __restrict__ out, int N)
{
    constexpr int FG  = F / 4;
    constexpr int EPW = 64 / FG;
    constexpr int U   = (F == 64) ? 8 : (F == 32 ? 4 : 2);

    const int lane = threadIdx.x & 63;
    const int wv   = threadIdx.x >> 6;
    const int i    = blockIdx.x * 4 + wv;
    if (i >= N) return;

    const int fg = lane % FG;
    const int eo = lane / FG;
    const int fb = fg * 4;

    float a0 = 0.f, a1 = 0.f, a2 = 0.f, a3 = 0.f;
    const int s = row_off[i], e = row_off[i + 1];
    int p = s + eo;
    for (; p + (U - 1) * EPW < e; p += U * EPW) {
        int js[U];
#pragma unroll
        for (int u = 0; u < U; ++u) js[u] = col[p + u * EPW];
        uint2 w[U];
#pragma unroll
        for (int u = 0; u < U; ++u)
            w[u] = *reinterpret_cast<const uint2*>(&g[(size_t)js[u] * F + fb]);
#pragma unroll
        for (int u = 0; u < U; ++u) {
            a0 += uaf(w[u].x << 16);
            a1 += uaf(w[u].x & 0xffff0000u);
            a2 += uaf(w[u].y << 16);
            a3 += uaf(w[u].y & 0xffff0000u);
        }
    }
    for (; p < e; p += EPW) {
        const uint2 w0 = *reinterpret_cast<const uint2*>(&g[(size_t)col[p] * F + fb]);
        a0 += uaf(w0.x << 16);
        a1 += uaf(w0.x & 0xffff0000u);
        a2 += uaf(w0.y << 16);
        a3 += uaf(w0.y & 0xffff0000u);
    }
#pragma unroll
    for (int off = FG; off < 64; off <<= 1) {
        a0 += __shfl_xor(a0, off);
        a1 += __shfl_xor(a1, off);
        a2 += __shfl_xor(a2, off);
        a3 += __shfl_xor(a3, off);
    }

    const uint2 ws = *reinterpret_cast<const uint2*>(&g[(size_t)i * F + fb]);
    const float di = dinv[i];
    float v0 = di * (a0 + uaf(ws.x << 16))         + bias[fb + 0];
    float v1 = di * (a1 + uaf(ws.x & 0xffff0000u)) + bias[fb + 1];
    float v2 = di * (a2 + uaf(ws.y << 16))         + bias[fb + 2];
    float v3 = di * (a3 + uaf(ws.y & 0xffff0000u)) + bias[fb + 3];
    if (MODE != 0) {
        const float4 pv = *reinterpret_cast<const float4*>(&pre[(size_t)i * F + fb]);
        v0 += pv.x; v1 += pv.y; v2 += pv.z; v3 += pv.w;
    }
    v0 = fmaxf(v0, 0.f); v1 = fmaxf(v1, 0.f);
    v2 = fmaxf(v2, 0.f); v3 = fmaxf(v3, 0.f);

    if (MODE != 2) {
        if (lane < FG) {
            uint2 o;
            o.x = (unsigned)f2bf(v0) | ((unsigned)f2bf(v1) << 16);
            o.y = (unsigned)f2bf(v2) | ((unsigned)f2bf(v3) << 16);
            *reinterpret_cast<uint2*>(&((ushort*)out)[(size_t)i * F + fb]) = o;
        }
    } else {
        float t = v0 * Wout[fb] + v1 * Wout[fb + 1] +
                  v2 * Wout[fb + 2] + v3 * Wout[fb + 3];
        t += __shfl_xor(t, 1);
        t += __shfl_xor(t, 2);
        if (lane == 0)
            ((float*)out)[i] = 1.0f / (1.0f + expf(-(t + bout[0])));
    }
}

// ---------------------------------------------------------------- launch

extern "C" void kernel_launch(void* const* d_in, const int* in_sizes, int n_in,
                              void* d_out, int out_size, void* d_ws, size_t ws_size,
                              hipStream_t stream)
{
    const float* x    = (const float*)d_in[0];
    const int*   edge = (const int*)d_in[1];
    const float* W1   = (const float*)d_in[2];
    const float* b1   = (const float*)d_in[3];
    const float* W2   = (const float*)d_in[4];
    const float* b2   = (const float*)d_in[5];
    const float* W3   = (const float*)d_in[6];
    const float* b3   = (const float*)d_in[7];
    const float* Ws02 = (const float*)d_in[8];
    const float* bs02 = (const float*)d_in[9];
    const float* Ws03 = (const float*)d_in[10];
    const float* bs03 = (const float*)d_in[11];
    const float* Ws13 = (const float*)d_in[12];
    const float* bs13 = (const float*)d_in[13];
    const float* Wout = (const float*)d_in[14];
    const float* bout = (const float*)d_in[15];

    const int N = in_sizes[0] / 256;
    const int E = in_sizes[1] / 2;
    const int* srcv = edge;
    const int* dstv = edge + E;
    const int nbuckets = (N + 255) >> 8;

    char* ws = (char*)d_ws;
    size_t off = 0;
    auto alloc = [&](size_t bytes) -> void* {
        void* p = ws + off;
        off += (bytes + 255) & ~(size_t)255;
        return p;
    };
    unsigned int* keys = (unsigned int*)alloc((size_t)E * 4);
    int*   col      = (int*)  alloc((size_t)E * 4);
    int*   bcount   = (int*)  alloc((size_t)NBUCK_MAX * 4);
    int*   bbase    = (int*)  alloc((size_t)NBUCK_MAX * 4);
    int*   bcursor  = (int*)  alloc((size_t)NBUCK_MAX * 4);
    int*   row_off  = (int*)  alloc((size_t)(N + 1) * 4);
    float* dinv     = (float*)alloc((size_t)N * 4);
    ushort* Wt0     = (ushort*)alloc((size_t)128 * 256 * 2);
    ushort* Wt1     = (ushort*)alloc((size_t)48 * 64 * 2);
    ushort* Wt2     = (ushort*)alloc((size_t)16 * 32 * 2);
    ushort* g1      = (ushort*)alloc((size_t)N * 64 * 2);
    ushort* x1      = (ushort*)alloc((size_t)N * 64 * 2);
    ushort* g2      = (ushort*)alloc((size_t)N * 32 * 2);
    ushort* x2      = (ushort*)alloc((size_t)N * 32 * 2);
    ushort* g3      = (ushort*)alloc((size_t)N * 16 * 2);
    float* pre2     = (float*)alloc((size_t)N * 32 * 4);
    float* pre3     = (float*)alloc((size_t)N * 16 * 4);

    // --- weight prep + graph build
    prep_weights_kernel<<<142, 256, 0, stream>>>(W1, Ws02, Ws03, W2, Ws13, W3,
                                                 Wt0, Wt1, Wt2);
    hipMemsetAsync(bcount, 0, (size_t)NBUCK_MAX * 4, stream);
    bucket_hist_kernel<<<1024, 256, 0, stream>>>(dstv, E, bcount, nbuckets);
    bucket_scan_kernel<<<1, 512, 0, stream>>>(bcount, bbase, bcursor, nbuckets);
    partition_kernel<<<(E + P1_CHUNK - 1) / P1_CHUNK, 256, 0, stream>>>(
        srcv, dstv, E, bcursor, keys, nbuckets);
    csr_build_kernel<<<nbuckets, 256, 0, stream>>>(
        keys, bbase, bcount, row_off, dinv, col, N, E);

    const int ab = (N + 3) / 4;

    // --- layer 1 (+ all x projections fused)
    gemm_mfma0<<<(N + 63) / 64, 256, 0, stream>>>(
        x, Wt0, bs02, bs03, dinv, (__hip_bfloat16*)g1, pre2, pre3, N);
    agg_kernel<64, 0><<<ab, 256, 0, stream>>>(g1, dinv, row_off, col,
                                              b1, nullptr, nullptr, nullptr, x1, N);
    // --- layer 2 (+ x1@Ws13 fused)
    gemm_mfma1<<<(N + 127) / 128, 256, 0, stream>>>(
        x1, Wt1, bs13, dinv, (__hip_bfloat16*)g2, pre3, N);
    agg_kernel<32, 1><<<ab, 256, 0, stream>>>(g2, dinv, row_off, col,
                                              b2, pre2, nullptr, nullptr, x2, N);
    // --- layer 3 + output head
    gemm_mfma2<<<(N + 127) / 128, 256, 0, stream>>>(
        x2, Wt2, dinv, (__hip_bfloat16*)g3, N);
    agg_kernel<16, 2><<<ab, 256, 0, stream>>>(g3, dinv, row_off, col,
                                              b3, pre3, Wout, bout, d_out, N);
}

// Round 7
// 477.335 us; speedup vs baseline: 1.0188x; 1.0188x over previous
//
#include <hip/hip_runtime.h>
#include <hip/hip_bf16.h>
#include <math.h>

// DenseGCN3Layer on MI355X — round 7.
// Changes vs r6:
//  * gemm_mfma0 rebuilt: whole 64x256 fp32 tile staged to LDS via
//    global_load_lds width=16 (one call per row -> perfectly coalesced 1KB),
//    chunk-XOR swizzle to kill the 16-way ds_read bank conflict (padding is
//    impossible with global_load_lds), B-fragments preloaded once into
//    registers, single __syncthreads, 8 barrier-free K-panels.
//  * everything else unchanged from r6.

#define NBUCK_MAX 512
#define P1_CHUNK 8192
#define EPT 32
#define BCAP 9216

typedef __attribute__((ext_vector_type(8))) short bfrag;   // 8 bf16 (4 VGPR)
typedef __attribute__((ext_vector_type(4))) float f4_t;    // acc

__device__ inline float uaf(unsigned u) { return __uint_as_float(u); }
__device__ inline ushort f2bf(float f) {
    __hip_bfloat16 b = __float2bfloat16(f);
    return *reinterpret_cast<ushort*>(&b);
}
__device__ inline bfrag cvt8(const float4 a, const float4 b) {
    union { ushort u[8]; bfrag f; } r;
    r.u[0] = f2bf(a.x); r.u[1] = f2bf(a.y); r.u[2] = f2bf(a.z); r.u[3] = f2bf(a.w);
    r.u[4] = f2bf(b.x); r.u[5] = f2bf(b.y); r.u[6] = f2bf(b.z); r.u[7] = f2bf(b.w);
    return r.f;
}
__device__ inline bfrag ld_bfrag(const ushort* p) {
    const uint4 raw = *reinterpret_cast<const uint4*>(p);
    return *reinterpret_cast<const bfrag*>(&raw);
}

// ---------------------------------------------------------------- build (r3)

__global__ __launch_bounds__(256) void bucket_hist_kernel(
    const int* __restrict__ dst, int E, int* __restrict__ bucket_count, int nbuckets)
{
    __shared__ int lhist[NBUCK_MAX];
    for (int i = threadIdx.x; i < nbuckets; i += 256) lhist[i] = 0;
    __syncthreads();
    const int stride = gridDim.x * 256;
    for (int e = blockIdx.x * 256 + threadIdx.x; e < E; e += stride)
        atomicAdd(&lhist[dst[e] >> 8], 1);
    __syncthreads();
    for (int i = threadIdx.x; i < nbuckets; i += 256) {
        int c = lhist[i];
        if (c) atomicAdd(&bucket_count[i], c);
    }
}

__global__ __launch_bounds__(512) void bucket_scan_kernel(
    const int* __restrict__ bucket_count, int* __restrict__ bucket_base,
    int* __restrict__ bucket_cursor, int nbuckets)
{
    __shared__ int tmp[512];
    const int tid = threadIdx.x;
    int v = (tid < nbuckets) ? bucket_count[tid] : 0;
    tmp[tid] = v;
    __syncthreads();
    for (int off = 1; off < 512; off <<= 1) {
        int t = (tid >= off) ? tmp[tid - off] : 0;
        __syncthreads();
        tmp[tid] += t;
        __syncthreads();
    }
    if (tid < nbuckets) {
        int base = tmp[tid] - v;
        bucket_base[tid]   = base;
        bucket_cursor[tid] = base;
    }
}

__global__ __launch_bounds__(256) void partition_kernel(
    const int* __restrict__ src, const int* __restrict__ dst, int E,
    int* __restrict__ bucket_cursor, unsigned int* __restrict__ keys, int nbuckets)
{
    __shared__ int hist[NBUCK_MAX];
    __shared__ int lofs[NBUCK_MAX];
    __shared__ int gbase[NBUCK_MAX];
    __shared__ int lcur[NBUCK_MAX];
    __shared__ int ssum[256];
    __shared__ unsigned int stage[P1_CHUNK];
    __shared__ int gidx[P1_CHUNK];

    const int tid = threadIdx.x;
    const int e0  = blockIdx.x * P1_CHUNK;
    const int nE  = min(P1_CHUNK, E - e0);

    for (int i = tid; i < NBUCK_MAX; i += 256) { hist[i] = 0; lcur[i] = 0; }
    __syncthreads();

    int myb[EPT];
    unsigned int mypk[EPT];
#pragma unroll
    for (int j = 0; j < EPT; ++j) {
        const int e = e0 + tid + j * 256;
        if (e < E) {
            const int d = dst[e];
            myb[j]  = d >> 8;
            mypk[j] = ((unsigned int)(d & 255) << 17) | (unsigned int)src[e];
            atomicAdd(&hist[myb[j]], 1);
        } else myb[j] = -1;
    }
    __syncthreads();

    int a0 = (2 * tid     < nbuckets) ? hist[2 * tid]     : 0;
    int a1 = (2 * tid + 1 < nbuckets) ? hist[2 * tid + 1] : 0;
    ssum[tid] = a0 + a1;
    __syncthreads();
    for (int off = 1; off < 256; off <<= 1) {
        int t = (tid >= off) ? ssum[tid - off] : 0;
        __syncthreads();
        ssum[tid] += t;
        __syncthreads();
    }
    const int ex = ssum[tid] - (a0 + a1);
    if (2 * tid     < nbuckets) lofs[2 * tid]     = ex;
    if (2 * tid + 1 < nbuckets) lofs[2 * tid + 1] = ex + a0;
    __syncthreads();

    for (int i = tid; i < nbuckets; i += 256)
        gbase[i] = atomicAdd(&bucket_cursor[i], hist[i]);
    __syncthreads();

#pragma unroll
    for (int j = 0; j < EPT; ++j) {
        if (myb[j] >= 0) {
            const int b = myb[j];
            const int l = lofs[b] + atomicAdd(&lcur[b], 1);
            stage[l] = mypk[j];
            gidx[l]  = gbase[b] - lofs[b] + l;
        }
    }
    __syncthreads();

    for (int i = tid; i < nE; i += 256)
        keys[gidx[i]] = stage[i];
}

__global__ __launch_bounds__(256) void csr_build_kernel(
    const unsigned int* __restrict__ keys, const int* __restrict__ bucket_base,
    const int* __restrict__ bucket_count,
    int* __restrict__ row_off, float* __restrict__ dinv, int* __restrict__ col,
    int N, int E)
{
    __shared__ unsigned int inb[BCAP];
    __shared__ int outv[BCAP];
    __shared__ int hist[256];
    __shared__ int lofs[256];
    __shared__ int ssum[256];

    const int tid  = threadIdx.x;
    const int b    = blockIdx.x;
    const int base = bucket_base[b];
    const int cnt  = min(bucket_count[b], BCAP);
    const int n0   = b << 8;
    const int nn   = min(256, N - n0);

    for (int i = tid; i < cnt; i += 256) inb[i] = keys[base + i];
    hist[tid] = 0;
    __syncthreads();

    for (int i = tid; i < cnt; i += 256)
        atomicAdd(&hist[inb[i] >> 17], 1);
    __syncthreads();

    ssum[tid] = hist[tid];
    __syncthreads();
    for (int off = 1; off < 256; off <<= 1) {
        int t = (tid >= off) ? ssum[tid - off] : 0;
        __syncthreads();
        ssum[tid] += t;
        __syncthreads();
    }
    lofs[tid] = ssum[tid] - hist[tid];

    if (tid < nn) {
        row_off[n0 + tid] = base + lofs[tid];
        dinv[n0 + tid]    = rsqrtf((float)hist[tid] + 1.0f);
    }
    if (b == 0 && tid == 0) row_off[N] = E;
    __syncthreads();

    hist[tid] = 0;
    __syncthreads();

    for (int i = tid; i < cnt; i += 256) {
        const unsigned int k = inb[i];
        const int node = k >> 17;
        const int l = lofs[node] + atomicAdd(&hist[node], 1);
        outv[l] = (int)(k & 0x1FFFF);
    }
    __syncthreads();

    for (int i = tid; i < cnt; i += 256)
        col[base + i] = outv[i];
}

// ---------------------------------------------------------------- weight prep

__global__ __launch_bounds__(256) void prep_weights_kernel(
    const float* __restrict__ W1, const float* __restrict__ Ws02,
    const float* __restrict__ Ws03, const float* __restrict__ W2,
    const float* __restrict__ Ws13, const float* __restrict__ W3,
    ushort* __restrict__ Wt0, ushort* __restrict__ Wt1, ushort* __restrict__ Wt2)
{
    int idx = blockIdx.x * 256 + threadIdx.x;
    if (idx < 32768) {
        int f = idx >> 8, k = idx & 255;
        float v = 0.f;
        if (f < 64)       v = W1[k * 64 + f];
        else if (f < 96)  v = Ws02[k * 32 + (f - 64)];
        else if (f < 112) v = Ws03[k * 16 + (f - 96)];
        Wt0[idx] = f2bf(v);
    } else if (idx < 32768 + 3072) {
        int t = idx - 32768;
        int f = t >> 6, k = t & 63;
        float v = (f < 32) ? W2[k * 32 + f] : Ws13[k * 16 + (f - 32)];
        Wt1[t] = f2bf(v);
    } else if (idx < 32768 + 3072 + 512) {
        int t = idx - 32768 - 3072;
        int f = t >> 5, k = t & 31;
        Wt2[t] = f2bf(W3[k * 16 + f]);
    }
}

// ---------------------------------------------------------------- MFMA GEMMs
// A-frag: A[m=lane&15][k=(lane>>4)*8+j]; B-frag: B[n=lane&15][k=...];
// C/D: col(f)=lane&15, row(n)=(lane>>4)*4+reg.

// MODE 0: x[N,256] fp32 @ Wt0[128][256] -> g1(bf16), pre2, pre3.
// 64-row tile staged to LDS via global_load_lds (coalesced, chunk-swizzled);
// B preloaded to registers; single barrier.
__global__ __launch_bounds__(256, 2) void gemm_mfma0(
    const float* __restrict__ X, const ushort* __restrict__ Wt0,
    const float* __restrict__ bs02, const float* __restrict__ bs03,
    const float* __restrict__ dinv,
    __hip_bfloat16* __restrict__ g1, float* __restrict__ pre2,
    float* __restrict__ pre3, int N)
{
    __shared__ __align__(16) float Xs[64 * 256];   // 64 KB, chunk-swizzled

    const int tid  = threadIdx.x;
    const int lane = tid & 63;
    const int wf   = tid >> 6;          // wave = f-slice [wf*32, wf*32+32)
    const int n0   = blockIdx.x * 64;
    const int mrow = lane & 15;
    const int kq   = (lane >> 4) * 8;   // k elem offset within a 32-panel

    // ---- B preload: 2 ft x 8 panels = 16 bfrags (divergent loads, once)
    bfrag bfr[2][8];
#pragma unroll
    for (int ft = 0; ft < 2; ++ft) {
        const ushort* wr = &Wt0[(size_t)(wf * 32 + ft * 16 + mrow) * 256 + kq];
#pragma unroll
        for (int p = 0; p < 8; ++p)
            bfr[ft][p] = ld_bfrag(&wr[p * 32]);
    }

    // ---- stage 64 rows x 1KB, one global_load_lds per row (lane-contiguous).
    // LDS slot s of row r holds global chunk (s ^ (r&7))  [16B chunks].
    {
        for (int i = 0; i < 16; ++i) {
            const int lrow = wf * 16 + i;
            const int grow = min(n0 + lrow, N - 1);
            const float* gsrc = X + (size_t)grow * 256 +
                                (size_t)((lane ^ (lrow & 7)) * 4);
            __builtin_amdgcn_global_load_lds(
                (const __attribute__((address_space(1))) unsigned int*)gsrc,
                (__attribute__((address_space(3))) unsigned int*)&Xs[lrow * 256],
                16, 0, 0);
        }
    }
    __syncthreads();   // drains vmcnt (barrier semantics)

    f4_t acc[4][2];
#pragma unroll
    for (int a = 0; a < 4; ++a)
#pragma unroll
        for (int b = 0; b < 2; ++b) acc[a][b] = {0.f, 0.f, 0.f, 0.f};

    const float4* Xs4 = reinterpret_cast<const float4*>(Xs);

#pragma unroll
    for (int p = 0; p < 8; ++p) {
        bfrag af[4];
#pragma unroll
        for (int mt = 0; mt < 4; ++mt) {
            const int r  = mt * 16 + mrow;
            const int c0 = p * 8 + (lane >> 4) * 2;
            const float4 u0 = Xs4[r * 64 + (c0 ^ (r & 7))];
            const float4 u1 = Xs4[r * 64 + ((c0 + 1) ^ (r & 7))];
            af[mt] = cvt8(u0, u1);
        }
#pragma unroll
        for (int mt = 0; mt < 4; ++mt)
#pragma unroll
            for (int ft = 0; ft < 2; ++ft)
                acc[mt][ft] = __builtin_amdgcn_mfma_f32_16x16x32_bf16(
                    af[mt], bfr[ft][p], acc[mt][ft], 0, 0, 0);
    }

    // ---- epilogue
#pragma unroll
    for (int mt = 0; mt < 4; ++mt) {
#pragma unroll
        for (int ft = 0; ft < 2; ++ft) {
            const int fg = wf * 32 + ft * 16 + mrow;
#pragma unroll
            for (int r = 0; r < 4; ++r) {
                const int n = n0 + mt * 16 + (lane >> 4) * 4 + r;
                if (n >= N) continue;
                const float a = acc[mt][ft][r];
                if (fg < 64) {
                    g1[(size_t)n * 64 + fg] = __float2bfloat16(dinv[n] * a);
                } else if (fg < 96) {
                    pre2[(size_t)n * 32 + (fg - 64)] = a + bs02[fg - 64];
                } else if (fg < 112) {
                    pre3[(size_t)n * 16 + (fg - 96)] = a + bs03[fg - 96];
                }
            }
        }
    }
}

// MODE 1: x1[N,64] bf16 @ Wt1[48][64] -> g2(bf16), pre3 += (. + bs13).  (r6)
__global__ __launch_bounds__(256) void gemm_mfma1(
    const ushort* __restrict__ X1, const ushort* __restrict__ Wt1,
    const float* __restrict__ bs13, const float* __restrict__ dinv,
    __hip_bfloat16* __restrict__ g2, float* __restrict__ pre3, int N)
{
    const int tid  = threadIdx.x;
    const int lane = tid & 63;
    const int wave = tid >> 6;
    const int n0   = blockIdx.x * 128 + wave * 32;
    const int mrow = lane & 15;
    const int kq   = (lane >> 4) * 8;

    f4_t acc[2][3];
#pragma unroll
    for (int a = 0; a < 2; ++a)
#pragma unroll
        for (int b = 0; b < 3; ++b) acc[a][b] = {0.f, 0.f, 0.f, 0.f};

    const ushort* xrow[2];
#pragma unroll
    for (int mt = 0; mt < 2; ++mt) {
        int r = n0 + mt * 16 + mrow;
        r = (r < N) ? r : (N - 1);
        xrow[mt] = &X1[(size_t)r * 64 + kq];
    }
    const ushort* wrow[3];
#pragma unroll
    for (int ft = 0; ft < 3; ++ft)
        wrow[ft] = &Wt1[(size_t)(ft * 16 + mrow) * 64 + kq];

#pragma unroll
    for (int p = 0; p < 2; ++p) {
        bfrag af[2], bf[3];
#pragma unroll
        for (int mt = 0; mt < 2; ++mt) af[mt] = ld_bfrag(&xrow[mt][p * 32]);
#pragma unroll
        for (int ft = 0; ft < 3; ++ft) bf[ft] = ld_bfrag(&wrow[ft][p * 32]);
#pragma unroll
        for (int mt = 0; mt < 2; ++mt)
#pragma unroll
            for (int ft = 0; ft < 3; ++ft)
                acc[mt][ft] = __builtin_amdgcn_mfma_f32_16x16x32_bf16(
                    af[mt], bf[ft], acc[mt][ft], 0, 0, 0);
    }

#pragma unroll
    for (int mt = 0; mt < 2; ++mt) {
#pragma unroll
        for (int ft = 0; ft < 3; ++ft) {
            const int fg = ft * 16 + mrow;
#pragma unroll
            for (int r = 0; r < 4; ++r) {
                const int n = n0 + mt * 16 + (lane >> 4) * 4 + r;
                if (n >= N) continue;
                const float a = acc[mt][ft][r];
                if (fg < 32) {
                    g2[(size_t)n * 32 + fg] = __float2bfloat16(dinv[n] * a);
                } else {
                    pre3[(size_t)n * 16 + (fg - 32)] += a + bs13[fg - 32];
                }
            }
        }
    }
}

// MODE 2: x2[N,32] bf16 @ Wt2[16][32] -> g3(bf16).  (r6)
__global__ __launch_bounds__(256) void gemm_mfma2(
    const ushort* __restrict__ X2, const ushort* __restrict__ Wt2,
    const float* __restrict__ dinv, __hip_bfloat16* __restrict__ g3, int N)
{
    const int tid  = threadIdx.x;
    const int lane = tid & 63;
    const int wave = tid >> 6;
    const int n0   = blockIdx.x * 128 + wave * 32;
    const int mrow = lane & 15;
    const int kq   = (lane >> 4) * 8;

    f4_t acc[2];
#pragma unroll
    for (int a = 0; a < 2; ++a) acc[a] = {0.f, 0.f, 0.f, 0.f};

    const bfrag bf = ld_bfrag(&Wt2[(size_t)mrow * 32 + kq]);
#pragma unroll
    for (int mt = 0; mt < 2; ++mt) {
        int r = n0 + mt * 16 + mrow;
        r = (r < N) ? r : (N - 1);
        const bfrag af = ld_bfrag(&X2[(size_t)r * 32 + kq]);
        acc[mt] = __builtin_amdgcn_mfma_f32_16x16x32_bf16(af, bf, acc[mt], 0, 0, 0);
    }

#pragma unroll
    for (int mt = 0; mt < 2; ++mt) {
#pragma unroll
        for (int r = 0; r < 4; ++r) {
            const int n = n0 + mt * 16 + (lane >> 4) * 4 + r;
            if (n >= N) continue;
            g3[(size_t)n * 16 + mrow] = __float2bfloat16(dinv[n] * acc[mt][r]);
        }
    }
}

// ---------------------------------------------------------------- aggregation

template<int F, int MODE>
__global__ __launch_bounds__(256) void agg_kernel(
    const ushort* __restrict__ g, const float* __restrict__ dinv,
    const int* __restrict__ row_off, const int* __restrict__ col,
    const float* __restrict__ bias, const float* __restrict__ pre,
    const float* __restrict__ Wout, const float* __restrict__ bout,
    void* __restrict__ out, int N)
{
    constexpr int FG  = F / 4;
    constexpr int EPW = 64 / FG;
    constexpr int U   = (F == 64) ? 8 : (F == 32 ? 4 : 2);

    const int lane = threadIdx.x & 63;
    const int wv   = threadIdx.x >> 6;
    const int i    = blockIdx.x * 4 + wv;
    if (i >= N) return;

    const int fg = lane % FG;
    const int eo = lane / FG;
    const int fb = fg * 4;

    float a0 = 0.f, a1 = 0.f, a2 = 0.f, a3 = 0.f;
    const int s = row_off[i], e = row_off[i + 1];
    int p = s + eo;
    for (; p + (U - 1) * EPW < e; p += U * EPW) {
        int js[U];
#pragma unroll
        for (int u = 0; u < U; ++u) js[u] = col[p + u * EPW];
        uint2 w[U];
#pragma unroll
        for (int u = 0; u < U; ++u)
            w[u] = *reinterpret_cast<const uint2*>(&g[(size_t)js[u] * F + fb]);
#pragma unroll
        for (int u = 0; u < U; ++u) {
            a0 += uaf(w[u].x << 16);
            a1 += uaf(w[u].x & 0xffff0000u);
            a2 += uaf(w[u].y << 16);
            a3 += uaf(w[u].y & 0xffff0000u);
        }
    }
    for (; p < e; p += EPW) {
        const uint2 w0 = *reinterpret_cast<const uint2*>(&g[(size_t)col[p] * F + fb]);
        a0 += uaf(w0.x << 16);
        a1 += uaf(w0.x & 0xffff0000u);
        a2 += uaf(w0.y << 16);
        a3 += uaf(w0.y & 0xffff0000u);
    }
#pragma unroll
    for (int off = FG; off < 64; off <<= 1) {
        a0 += __shfl_xor(a0, off);
        a1 += __shfl_xor(a1, off);
        a2 += __shfl_xor(a2, off);
        a3 += __shfl_xor(a3, off);
    }

    const uint2 ws = *reinterpret_cast<const uint2*>(&g[(size_t)i * F + fb]);
    const float di = dinv[i];
    float v0 = di * (a0 + uaf(ws.x << 16))         + bias[fb + 0];
    float v1 = di * (a1 + uaf(ws.x & 0xffff0000u)) + bias[fb + 1];
    float v2 = di * (a2 + uaf(ws.y << 16))         + bias[fb + 2];
    float v3 = di * (a3 + uaf(ws.y & 0xffff0000u)) + bias[fb + 3];
    if (MODE != 0) {
        const float4 pv = *reinterpret_cast<const float4*>(&pre[(size_t)i * F + fb]);
        v0 += pv.x; v1 += pv.y; v2 += pv.z; v3 += pv.w;
    }
    v0 = fmaxf(v0, 0.f); v1 = fmaxf(v1, 0.f);
    v2 = fmaxf(v2, 0.f); v3 = fmaxf(v3, 0.f);

    if (MODE != 2) {
        if (lane < FG) {
            uint2 o;
            o.x = (unsigned)f2bf(v0) | ((unsigned)f2bf(v1) << 16);
            o.y = (unsigned)f2bf(v2) | ((unsigned)f2bf(v3) << 16);
            *reinterpret_cast<uint2*>(&((ushort*)out)[(size_t)i * F + fb]) = o;
        }
    } else {
        float t = v0 * Wout[fb] + v1 * Wout[fb + 1] +
                  v2 * Wout[fb + 2] + v3 * Wout[fb + 3];
        t += __shfl_xor(t, 1);
        t += __shfl_xor(t, 2);
        if (lane == 0)
            ((float*)out)[i] = 1.0f / (1.0f + expf(-(t + bout[0])));
    }
}

// ---------------------------------------------------------------- launch

extern "C" void kernel_launch(void* const* d_in, const int* in_sizes, int n_in,
                              void* d_out, int out_size, void* d_ws, size_t ws_size,
                              hipStream_t stream)
{
    const float* x    = (const float*)d_in[0];
    const int*   edge = (const int*)d_in[1];
    const float* W1   = (const float*)d_in[2];
    const float* b1   = (const float*)d_in[3];
    const float* W2   = (const float*)d_in[4];
    const float* b2   = (const float*)d_in[5];
    const float* W3   = (const float*)d_in[6];
    const float* b3   = (const float*)d_in[7];
    const float* Ws02 = (const float*)d_in[8];
    const float* bs02 = (const float*)d_in[9];
    const float* Ws03 = (const float*)d_in[10];
    const float* bs03 = (const float*)d_in[11];
    const float* Ws13 = (const float*)d_in[12];
    const float* bs13 = (const float*)d_in[13];
    const float* Wout = (const float*)d_in[14];
    const float* bout = (const float*)d_in[15];

    const int N = in_sizes[0] / 256;
    const int E = in_sizes[1] / 2;
    const int* srcv = edge;
    const int* dstv = edge + E;
    const int nbuckets = (N + 255) >> 8;

    char* ws = (char*)d_ws;
    size_t off = 0;
    auto alloc = [&](size_t bytes) -> void* {
        void* p = ws + off;
        off += (bytes + 255) & ~(size_t)255;
        return p;
    };
    unsigned int* keys = (unsigned int*)alloc((size_t)E * 4);
    int*   col      = (int*)  alloc((size_t)E * 4);
    int*   bcount   = (int*)  alloc((size_t)NBUCK_MAX * 4);
    int*   bbase    = (int*)  alloc((size_t)NBUCK_MAX * 4);
    int*   bcursor  = (int*)  alloc((size_t)NBUCK_MAX * 4);
    int*   row_off  = (int*)  alloc((size_t)(N + 1) * 4);
    float* dinv     = (float*)alloc((size_t)N * 4);
    ushort* Wt0     = (ushort*)alloc((size_t)128 * 256 * 2);
    ushort* Wt1     = (ushort*)alloc((size_t)48 * 64 * 2);
    ushort* Wt2     = (ushort*)alloc((size_t)16 * 32 * 2);
    ushort* g1      = (ushort*)alloc((size_t)N * 64 * 2);
    ushort* x1      = (ushort*)alloc((size_t)N * 64 * 2);
    ushort* g2      = (ushort*)alloc((size_t)N * 32 * 2);
    ushort* x2      = (ushort*)alloc((size_t)N * 32 * 2);
    ushort* g3      = (ushort*)alloc((size_t)N * 16 * 2);
    float* pre2     = (float*)alloc((size_t)N * 32 * 4);
    float* pre3     = (float*)alloc((size_t)N * 16 * 4);

    // --- weight prep + graph build
    prep_weights_kernel<<<142, 256, 0, stream>>>(W1, Ws02, Ws03, W2, Ws13, W3,
                                                 Wt0, Wt1, Wt2);
    hipMemsetAsync(bcount, 0, (size_t)NBUCK_MAX * 4, stream);
    bucket_hist_kernel<<<1024, 256, 0, stream>>>(dstv, E, bcount, nbuckets);
    bucket_scan_kernel<<<1, 512, 0, stream>>>(bcount, bbase, bcursor, nbuckets);
    partition_kernel<<<(E + P1_CHUNK - 1) / P1_CHUNK, 256, 0, stream>>>(
        srcv, dstv, E, bcursor, keys, nbuckets);
    csr_build_kernel<<<nbuckets, 256, 0, stream>>>(
        keys, bbase, bcount, row_off, dinv, col, N, E);

    const int ab = (N + 3) / 4;

    // --- layer 1 (+ all x projections fused)
    gemm_mfma0<<<(N + 63) / 64, 256, 0, stream>>>(
        x, Wt0, bs02, bs03, dinv, (__hip_bfloat16*)g1, pre2, pre3, N);
    agg_kernel<64, 0><<<ab, 256, 0, stream>>>(g1, dinv, row_off, col,
                                              b1, nullptr, nullptr, nullptr, x1, N);
    // --- layer 2 (+ x1@Ws13 fused)
    gemm_mfma1<<<(N + 127) / 128, 256, 0, stream>>>(
        x1, Wt1, bs13, dinv, (__hip_bfloat16*)g2, pre3, N);
    agg_kernel<32, 1><<<ab, 256, 0, stream>>>(g2, dinv, row_off, col,
                                              b2, pre2, nullptr, nullptr, x2, N);
    // --- layer 3 + output head
    gemm_mfma2<<<(N + 127) / 128, 256, 0, stream>>>(
        x2, Wt2, dinv, (__hip_bfloat16*)g3, N);
    agg_kernel<16, 2><<<ab, 256, 0, stream>>>(g3, dinv, row_off, col,
                                              b3, pre3, Wout, bout, d_out, N);
}

// Round 8
// 444.103 us; speedup vs baseline: 1.0950x; 1.0748x over previous
//
#include <hip/hip_runtime.h>
#include <hip/hip_bf16.h>
#include <math.h>

// DenseGCN3Layer on MI355X — round 8.
// Changes vs r7:
//  * agg_kernel: predicated burst (clamped col index + 0/1-mask fmaf) replaces
//    the serial cleanup loop. Tail now costs one burst latency instead of up
//    to 8 dependent L2/L3 round-trips. All loads always in flight.
//  * everything else unchanged from r7.

#define NBUCK_MAX 512
#define P1_CHUNK 8192
#define EPT 32
#define BCAP 9216

typedef __attribute__((ext_vector_type(8))) short bfrag;   // 8 bf16 (4 VGPR)
typedef __attribute__((ext_vector_type(4))) float f4_t;    // acc

__device__ inline float uaf(unsigned u) { return __uint_as_float(u); }
__device__ inline ushort f2bf(float f) {
    __hip_bfloat16 b = __float2bfloat16(f);
    return *reinterpret_cast<ushort*>(&b);
}
__device__ inline bfrag cvt8(const float4 a, const float4 b) {
    union { ushort u[8]; bfrag f; } r;
    r.u[0] = f2bf(a.x); r.u[1] = f2bf(a.y); r.u[2] = f2bf(a.z); r.u[3] = f2bf(a.w);
    r.u[4] = f2bf(b.x); r.u[5] = f2bf(b.y); r.u[6] = f2bf(b.z); r.u[7] = f2bf(b.w);
    return r.f;
}
__device__ inline bfrag ld_bfrag(const ushort* p) {
    const uint4 raw = *reinterpret_cast<const uint4*>(p);
    return *reinterpret_cast<const bfrag*>(&raw);
}

// ---------------------------------------------------------------- build (r3)

__global__ __launch_bounds__(256) void bucket_hist_kernel(
    const int* __restrict__ dst, int E, int* __restrict__ bucket_count, int nbuckets)
{
    __shared__ int lhist[NBUCK_MAX];
    for (int i = threadIdx.x; i < nbuckets; i += 256) lhist[i] = 0;
    __syncthreads();
    const int stride = gridDim.x * 256;
    for (int e = blockIdx.x * 256 + threadIdx.x; e < E; e += stride)
        atomicAdd(&lhist[dst[e] >> 8], 1);
    __syncthreads();
    for (int i = threadIdx.x; i < nbuckets; i += 256) {
        int c = lhist[i];
        if (c) atomicAdd(&bucket_count[i], c);
    }
}

__global__ __launch_bounds__(512) void bucket_scan_kernel(
    const int* __restrict__ bucket_count, int* __restrict__ bucket_base,
    int* __restrict__ bucket_cursor, int nbuckets)
{
    __shared__ int tmp[512];
    const int tid = threadIdx.x;
    int v = (tid < nbuckets) ? bucket_count[tid] : 0;
    tmp[tid] = v;
    __syncthreads();
    for (int off = 1; off < 512; off <<= 1) {
        int t = (tid >= off) ? tmp[tid - off] : 0;
        __syncthreads();
        tmp[tid] += t;
        __syncthreads();
    }
    if (tid < nbuckets) {
        int base = tmp[tid] - v;
        bucket_base[tid]   = base;
        bucket_cursor[tid] = base;
    }
}

__global__ __launch_bounds__(256) void partition_kernel(
    const int* __restrict__ src, const int* __restrict__ dst, int E,
    int* __restrict__ bucket_cursor, unsigned int* __restrict__ keys, int nbuckets)
{
    __shared__ int hist[NBUCK_MAX];
    __shared__ int lofs[NBUCK_MAX];
    __shared__ int gbase[NBUCK_MAX];
    __shared__ int lcur[NBUCK_MAX];
    __shared__ int ssum[256];
    __shared__ unsigned int stage[P1_CHUNK];
    __shared__ int gidx[P1_CHUNK];

    const int tid = threadIdx.x;
    const int e0  = blockIdx.x * P1_CHUNK;
    const int nE  = min(P1_CHUNK, E - e0);

    for (int i = tid; i < NBUCK_MAX; i += 256) { hist[i] = 0; lcur[i] = 0; }
    __syncthreads();

    int myb[EPT];
    unsigned int mypk[EPT];
#pragma unroll
    for (int j = 0; j < EPT; ++j) {
        const int e = e0 + tid + j * 256;
        if (e < E) {
            const int d = dst[e];
            myb[j]  = d >> 8;
            mypk[j] = ((unsigned int)(d & 255) << 17) | (unsigned int)src[e];
            atomicAdd(&hist[myb[j]], 1);
        } else myb[j] = -1;
    }
    __syncthreads();

    int a0 = (2 * tid     < nbuckets) ? hist[2 * tid]     : 0;
    int a1 = (2 * tid + 1 < nbuckets) ? hist[2 * tid + 1] : 0;
    ssum[tid] = a0 + a1;
    __syncthreads();
    for (int off = 1; off < 256; off <<= 1) {
        int t = (tid >= off) ? ssum[tid - off] : 0;
        __syncthreads();
        ssum[tid] += t;
        __syncthreads();
    }
    const int ex = ssum[tid] - (a0 + a1);
    if (2 * tid     < nbuckets) lofs[2 * tid]     = ex;
    if (2 * tid + 1 < nbuckets) lofs[2 * tid + 1] = ex + a0;
    __syncthreads();

    for (int i = tid; i < nbuckets; i += 256)
        gbase[i] = atomicAdd(&bucket_cursor[i], hist[i]);
    __syncthreads();

#pragma unroll
    for (int j = 0; j < EPT; ++j) {
        if (myb[j] >= 0) {
            const int b = myb[j];
            const int l = lofs[b] + atomicAdd(&lcur[b], 1);
            stage[l] = mypk[j];
            gidx[l]  = gbase[b] - lofs[b] + l;
        }
    }
    __syncthreads();

    for (int i = tid; i < nE; i += 256)
        keys[gidx[i]] = stage[i];
}

__global__ __launch_bounds__(256) void csr_build_kernel(
    const unsigned int* __restrict__ keys, const int* __restrict__ bucket_base,
    const int* __restrict__ bucket_count,
    int* __restrict__ row_off, float* __restrict__ dinv, int* __restrict__ col,
    int N, int E)
{
    __shared__ unsigned int inb[BCAP];
    __shared__ int outv[BCAP];
    __shared__ int hist[256];
    __shared__ int lofs[256];
    __shared__ int ssum[256];

    const int tid  = threadIdx.x;
    const int b    = blockIdx.x;
    const int base = bucket_base[b];
    const int cnt  = min(bucket_count[b], BCAP);
    const int n0   = b << 8;
    const int nn   = min(256, N - n0);

    for (int i = tid; i < cnt; i += 256) inb[i] = keys[base + i];
    hist[tid] = 0;
    __syncthreads();

    for (int i = tid; i < cnt; i += 256)
        atomicAdd(&hist[inb[i] >> 17], 1);
    __syncthreads();

    ssum[tid] = hist[tid];
    __syncthreads();
    for (int off = 1; off < 256; off <<= 1) {
        int t = (tid >= off) ? ssum[tid - off] : 0;
        __syncthreads();
        ssum[tid] += t;
        __syncthreads();
    }
    lofs[tid] = ssum[tid] - hist[tid];

    if (tid < nn) {
        row_off[n0 + tid] = base + lofs[tid];
        dinv[n0 + tid]    = rsqrtf((float)hist[tid] + 1.0f);
    }
    if (b == 0 && tid == 0) row_off[N] = E;
    __syncthreads();

    hist[tid] = 0;
    __syncthreads();

    for (int i = tid; i < cnt; i += 256) {
        const unsigned int k = inb[i];
        const int node = k >> 17;
        const int l = lofs[node] + atomicAdd(&hist[node], 1);
        outv[l] = (int)(k & 0x1FFFF);
    }
    __syncthreads();

    for (int i = tid; i < cnt; i += 256)
        col[base + i] = outv[i];
}

// ---------------------------------------------------------------- weight prep

__global__ __launch_bounds__(256) void prep_weights_kernel(
    const float* __restrict__ W1, const float* __restrict__ Ws02,
    const float* __restrict__ Ws03, const float* __restrict__ W2,
    const float* __restrict__ Ws13, const float* __restrict__ W3,
    ushort* __restrict__ Wt0, ushort* __restrict__ Wt1, ushort* __restrict__ Wt2)
{
    int idx = blockIdx.x * 256 + threadIdx.x;
    if (idx < 32768) {
        int f = idx >> 8, k = idx & 255;
        float v = 0.f;
        if (f < 64)       v = W1[k * 64 + f];
        else if (f < 96)  v = Ws02[k * 32 + (f - 64)];
        else if (f < 112) v = Ws03[k * 16 + (f - 96)];
        Wt0[idx] = f2bf(v);
    } else if (idx < 32768 + 3072) {
        int t = idx - 32768;
        int f = t >> 6, k = t & 63;
        float v = (f < 32) ? W2[k * 32 + f] : Ws13[k * 16 + (f - 32)];
        Wt1[t] = f2bf(v);
    } else if (idx < 32768 + 3072 + 512) {
        int t = idx - 32768 - 3072;
        int f = t >> 5, k = t & 31;
        Wt2[t] = f2bf(W3[k * 16 + f]);
    }
}

// ---------------------------------------------------------------- MFMA GEMMs
// A-frag: A[m=lane&15][k=(lane>>4)*8+j]; B-frag: B[n=lane&15][k=...];
// C/D: col(f)=lane&15, row(n)=(lane>>4)*4+reg.

// MODE 0: x[N,256] fp32 @ Wt0[128][256] -> g1(bf16), pre2, pre3.  (r7)
__global__ __launch_bounds__(256, 2) void gemm_mfma0(
    const float* __restrict__ X, const ushort* __restrict__ Wt0,
    const float* __restrict__ bs02, const float* __restrict__ bs03,
    const float* __restrict__ dinv,
    __hip_bfloat16* __restrict__ g1, float* __restrict__ pre2,
    float* __restrict__ pre3, int N)
{
    __shared__ __align__(16) float Xs[64 * 256];   // 64 KB, chunk-swizzled

    const int tid  = threadIdx.x;
    const int lane = tid & 63;
    const int wf   = tid >> 6;          // wave = f-slice [wf*32, wf*32+32)
    const int n0   = blockIdx.x * 64;
    const int mrow = lane & 15;
    const int kq   = (lane >> 4) * 8;

    bfrag bfr[2][8];
#pragma unroll
    for (int ft = 0; ft < 2; ++ft) {
        const ushort* wr = &Wt0[(size_t)(wf * 32 + ft * 16 + mrow) * 256 + kq];
#pragma unroll
        for (int p = 0; p < 8; ++p)
            bfr[ft][p] = ld_bfrag(&wr[p * 32]);
    }

    {
        for (int i = 0; i < 16; ++i) {
            const int lrow = wf * 16 + i;
            const int grow = min(n0 + lrow, N - 1);
            const float* gsrc = X + (size_t)grow * 256 +
                                (size_t)((lane ^ (lrow & 7)) * 4);
            __builtin_amdgcn_global_load_lds(
                (const __attribute__((address_space(1))) unsigned int*)gsrc,
                (__attribute__((address_space(3))) unsigned int*)&Xs[lrow * 256],
                16, 0, 0);
        }
    }
    __syncthreads();

    f4_t acc[4][2];
#pragma unroll
    for (int a = 0; a < 4; ++a)
#pragma unroll
        for (int b = 0; b < 2; ++b) acc[a][b] = {0.f, 0.f, 0.f, 0.f};

    const float4* Xs4 = reinterpret_cast<const float4*>(Xs);

#pragma unroll
    for (int p = 0; p < 8; ++p) {
        bfrag af[4];
#pragma unroll
        for (int mt = 0; mt < 4; ++mt) {
            const int r  = mt * 16 + mrow;
            const int c0 = p * 8 + (lane >> 4) * 2;
            const float4 u0 = Xs4[r * 64 + (c0 ^ (r & 7))];
            const float4 u1 = Xs4[r * 64 + ((c0 + 1) ^ (r & 7))];
            af[mt] = cvt8(u0, u1);
        }
#pragma unroll
        for (int mt = 0; mt < 4; ++mt)
#pragma unroll
            for (int ft = 0; ft < 2; ++ft)
                acc[mt][ft] = __builtin_amdgcn_mfma_f32_16x16x32_bf16(
                    af[mt], bfr[ft][p], acc[mt][ft], 0, 0, 0);
    }

#pragma unroll
    for (int mt = 0; mt < 4; ++mt) {
#pragma unroll
        for (int ft = 0; ft < 2; ++ft) {
            const int fg = wf * 32 + ft * 16 + mrow;
#pragma unroll
            for (int r = 0; r < 4; ++r) {
                const int n = n0 + mt * 16 + (lane >> 4) * 4 + r;
                if (n >= N) continue;
                const float a = acc[mt][ft][r];
                if (fg < 64) {
                    g1[(size_t)n * 64 + fg] = __float2bfloat16(dinv[n] * a);
                } else if (fg < 96) {
                    pre2[(size_t)n * 32 + (fg - 64)] = a + bs02[fg - 64];
                } else if (fg < 112) {
                    pre3[(size_t)n * 16 + (fg - 96)] = a + bs03[fg - 96];
                }
            }
        }
    }
}

// MODE 1: x1[N,64] bf16 @ Wt1[48][64] -> g2(bf16), pre3 += (. + bs13).  (r6)
__global__ __launch_bounds__(256) void gemm_mfma1(
    const ushort* __restrict__ X1, const ushort* __restrict__ Wt1,
    const float* __restrict__ bs13, const float* __restrict__ dinv,
    __hip_bfloat16* __restrict__ g2, float* __restrict__ pre3, int N)
{
    const int tid  = threadIdx.x;
    const int lane = tid & 63;
    const int wave = tid >> 6;
    const int n0   = blockIdx.x * 128 + wave * 32;
    const int mrow = lane & 15;
    const int kq   = (lane >> 4) * 8;

    f4_t acc[2][3];
#pragma unroll
    for (int a = 0; a < 2; ++a)
#pragma unroll
        for (int b = 0; b < 3; ++b) acc[a][b] = {0.f, 0.f, 0.f, 0.f};

    const ushort* xrow[2];
#pragma unroll
    for (int mt = 0; mt < 2; ++mt) {
        int r = n0 + mt * 16 + mrow;
        r = (r < N) ? r : (N - 1);
        xrow[mt] = &X1[(size_t)r * 64 + kq];
    }
    const ushort* wrow[3];
#pragma unroll
    for (int ft = 0; ft < 3; ++ft)
        wrow[ft] = &Wt1[(size_t)(ft * 16 + mrow) * 64 + kq];

#pragma unroll
    for (int p = 0; p < 2; ++p) {
        bfrag af[2], bf[3];
#pragma unroll
        for (int mt = 0; mt < 2; ++mt) af[mt] = ld_bfrag(&xrow[mt][p * 32]);
#pragma unroll
        for (int ft = 0; ft < 3; ++ft) bf[ft] = ld_bfrag(&wrow[ft][p * 32]);
#pragma unroll
        for (int mt = 0; mt < 2; ++mt)
#pragma unroll
            for (int ft = 0; ft < 3; ++ft)
                acc[mt][ft] = __builtin_amdgcn_mfma_f32_16x16x32_bf16(
                    af[mt], bf[ft], acc[mt][ft], 0, 0, 0);
    }

#pragma unroll
    for (int mt = 0; mt < 2; ++mt) {
#pragma unroll
        for (int ft = 0; ft < 3; ++ft) {
            const int fg = ft * 16 + mrow;
#pragma unroll
            for (int r = 0; r < 4; ++r) {
                const int n = n0 + mt * 16 + (lane >> 4) * 4 + r;
                if (n >= N) continue;
                const float a = acc[mt][ft][r];
                if (fg < 32) {
                    g2[(size_t)n * 32 + fg] = __float2bfloat16(dinv[n] * a);
                } else {
                    pre3[(size_t)n * 16 + (fg - 32)] += a + bs13[fg - 32];
                }
            }
        }
    }
}

// MODE 2: x2[N,32] bf16 @ Wt2[16][32] -> g3(bf16).  (r6)
__global__ __launch_bounds__(256) void gemm_mfma2(
    const ushort* __restrict__ X2, const ushort* __restrict__ Wt2,
    const float* __restrict__ dinv, __hip_bfloat16* __restrict__ g3, int N)
{
    const int tid  = threadIdx.x;
    const int lane = tid & 63;
    const int wave = tid >> 6;
    const int n0   = blockIdx.x * 128 + wave * 32;
    const int mrow = lane & 15;
    const int kq   = (lane >> 4) * 8;

    f4_t acc[2];
#pragma unroll
    for (int a = 0; a < 2; ++a) acc[a] = {0.f, 0.f, 0.f, 0.f};

    const bfrag bf = ld_bfrag(&Wt2[(size_t)mrow * 32 + kq]);
#pragma unroll
    for (int mt = 0; mt < 2; ++mt) {
        int r = n0 + mt * 16 + mrow;
        r = (r < N) ? r : (N - 1);
        const bfrag af = ld_bfrag(&X2[(size_t)r * 32 + kq]);
        acc[mt] = __builtin_amdgcn_mfma_f32_16x16x32_bf16(af, bf, acc[mt], 0, 0, 0);
    }

#pragma unroll
    for (int mt = 0; mt < 2; ++mt) {
#pragma unroll
        for (int r = 0; r < 4; ++r) {
            const int n = n0 + mt * 16 + (lane >> 4) * 4 + r;
            if (n >= N) continue;
            g3[(size_t)n * 16 + mrow] = __float2bfloat16(dinv[n] * acc[mt][r]);
        }
    }
}

// ---------------------------------------------------------------- aggregation
// One wave/node, 4 feats per lane (uint2), FG=F/4 lanes per edge, EPW edge
// slots, U-deep PREDICATED burst: clamped col index + 0/1-mask fmaf.
// No serial cleanup loop — tail costs one burst latency.

template<int F, int MODE>
__global__ __launch_bounds__(256) void agg_kernel(
    const ushort* __restrict__ g, const float* __restrict__ dinv,
    const int* __restrict__ row_off, const int* __restrict__ col,
    const float* __restrict__ bias, const float* __restrict__ pre,
    const float* __restrict__ Wout, const float* __restrict__ bout,
    void* __restrict__ out, int N)
{
    constexpr int FG  = F / 4;
    constexpr int EPW = 64 / FG;
    constexpr int U   = (F == 64) ? 8 : (F == 32 ? 4 : 2);   // U*EPW = 32 slots

    const int lane = threadIdx.x & 63;
    const int wv   = threadIdx.x >> 6;
    const int i    = blockIdx.x * 4 + wv;
    if (i >= N) return;

    const int fg = lane % FG;
    const int eo = lane / FG;
    const int fb = fg * 4;

    float a0 = 0.f, a1 = 0.f, a2 = 0.f, a3 = 0.f;
    const int s = row_off[i], e = row_off[i + 1];
    for (int p = s + eo; p < e; p += U * EPW) {
        int js[U];
        float m[U];
#pragma unroll
        for (int u = 0; u < U; ++u) {
            const int q = p + u * EPW;
            m[u]  = (q < e) ? 1.0f : 0.0f;
            js[u] = col[min(q, e - 1)];
        }
        uint2 w[U];
#pragma unroll
        for (int u = 0; u < U; ++u)
            w[u] = *reinterpret_cast<const uint2*>(&g[(size_t)js[u] * F + fb]);
#pragma unroll
        for (int u = 0; u < U; ++u) {
            a0 = fmaf(m[u], uaf(w[u].x << 16),         a0);
            a1 = fmaf(m[u], uaf(w[u].x & 0xffff0000u), a1);
            a2 = fmaf(m[u], uaf(w[u].y << 16),         a2);
            a3 = fmaf(m[u], uaf(w[u].y & 0xffff0000u), a3);
        }
    }
#pragma unroll
    for (int off = FG; off < 64; off <<= 1) {
        a0 += __shfl_xor(a0, off);
        a1 += __shfl_xor(a1, off);
        a2 += __shfl_xor(a2, off);
        a3 += __shfl_xor(a3, off);
    }

    const uint2 ws = *reinterpret_cast<const uint2*>(&g[(size_t)i * F + fb]);
    const float di = dinv[i];
    float v0 = di * (a0 + uaf(ws.x << 16))         + bias[fb + 0];
    float v1 = di * (a1 + uaf(ws.x & 0xffff0000u)) + bias[fb + 1];
    float v2 = di * (a2 + uaf(ws.y << 16))         + bias[fb + 2];
    float v3 = di * (a3 + uaf(ws.y & 0xffff0000u)) + bias[fb + 3];
    if (MODE != 0) {
        const float4 pv = *reinterpret_cast<const float4*>(&pre[(size_t)i * F + fb]);
        v0 += pv.x; v1 += pv.y; v2 += pv.z; v3 += pv.w;
    }
    v0 = fmaxf(v0, 0.f); v1 = fmaxf(v1, 0.f);
    v2 = fmaxf(v2, 0.f); v3 = fmaxf(v3, 0.f);

    if (MODE != 2) {
        if (lane < FG) {
            uint2 o;
            o.x = (unsigned)f2bf(v0) | ((unsigned)f2bf(v1) << 16);
            o.y = (unsigned)f2bf(v2) | ((unsigned)f2bf(v3) << 16);
            *reinterpret_cast<uint2*>(&((ushort*)out)[(size_t)i * F + fb]) = o;
        }
    } else {
        float t = v0 * Wout[fb] + v1 * Wout[fb + 1] +
                  v2 * Wout[fb + 2] + v3 * Wout[fb + 3];
        t += __shfl_xor(t, 1);
        t += __shfl_xor(t, 2);
        if (lane == 0)
            ((float*)out)[i] = 1.0f / (1.0f + expf(-(t + bout[0])));
    }
}

// ---------------------------------------------------------------- launch

extern "C" void kernel_launch(void* const* d_in, const int* in_sizes, int n_in,
                              void* d_out, int out_size, void* d_ws, size_t ws_size,
                              hipStream_t stream)
{
    const float* x    = (const float*)d_in[0];
    const int*   edge = (const int*)d_in[1];
    const float* W1   = (const float*)d_in[2];
    const float* b1   = (const float*)d_in[3];
    const float* W2   = (const float*)d_in[4];
    const float* b2   = (const float*)d_in[5];
    const float* W3   = (const float*)d_in[6];
    const float* b3   = (const float*)d_in[7];
    const float* Ws02 = (const float*)d_in[8];
    const float* bs02 = (const float*)d_in[9];
    const float* Ws03 = (const float*)d_in[10];
    const float* bs03 = (const float*)d_in[11];
    const float* Ws13 = (const float*)d_in[12];
    const float* bs13 = (const float*)d_in[13];
    const float* Wout = (const float*)d_in[14];
    const float* bout = (const float*)d_in[15];

    const int N = in_sizes[0] / 256;
    const int E = in_sizes[1] / 2;
    const int* srcv = edge;
    const int* dstv = edge + E;
    const int nbuckets = (N + 255) >> 8;

    char* ws = (char*)d_ws;
    size_t off = 0;
    auto alloc = [&](size_t bytes) -> void* {
        void* p = ws + off;
        off += (bytes + 255) & ~(size_t)255;
        return p;
    };
    unsigned int* keys = (unsigned int*)alloc((size_t)E * 4);
    int*   col      = (int*)  alloc((size_t)E * 4);
    int*   bcount   = (int*)  alloc((size_t)NBUCK_MAX * 4);
    int*   bbase    = (int*)  alloc((size_t)NBUCK_MAX * 4);
    int*   bcursor  = (int*)  alloc((size_t)NBUCK_MAX * 4);
    int*   row_off  = (int*)  alloc((size_t)(N + 1) * 4);
    float* dinv     = (float*)alloc((size_t)N * 4);
    ushort* Wt0     = (ushort*)alloc((size_t)128 * 256 * 2);
    ushort* Wt1     = (ushort*)alloc((size_t)48 * 64 * 2);
    ushort* Wt2     = (ushort*)alloc((size_t)16 * 32 * 2);
    ushort* g1      = (ushort*)alloc((size_t)N * 64 * 2);
    ushort* x1      = (ushort*)alloc((size_t)N * 64 * 2);
    ushort* g2      = (ushort*)alloc((size_t)N * 32 * 2);
    ushort* x2      = (ushort*)alloc((size_t)N * 32 * 2);
    ushort* g3      = (ushort*)alloc((size_t)N * 16 * 2);
    float* pre2     = (float*)alloc((size_t)N * 32 * 4);
    float* pre3     = (float*)alloc((size_t)N * 16 * 4);

    // --- weight prep + graph build
    prep_weights_kernel<<<142, 256, 0, stream>>>(W1, Ws02, Ws03, W2, Ws13, W3,
                                                 Wt0, Wt1, Wt2);
    hipMemsetAsync(bcount, 0, (size_t)NBUCK_MAX * 4, stream);
    bucket_hist_kernel<<<1024, 256, 0, stream>>>(dstv, E, bcount, nbuckets);
    bucket_scan_kernel<<<1, 512, 0, stream>>>(bcount, bbase, bcursor, nbuckets);
    partition_kernel<<<(E + P1_CHUNK - 1) / P1_CHUNK, 256, 0, stream>>>(
        srcv, dstv, E, bcursor, keys, nbuckets);
    csr_build_kernel<<<nbuckets, 256, 0, stream>>>(
        keys, bbase, bcount, row_off, dinv, col, N, E);

    const int ab = (N + 3) / 4;

    // --- layer 1 (+ all x projections fused)
    gemm_mfma0<<<(N + 63) / 64, 256, 0, stream>>>(
        x, Wt0, bs02, bs03, dinv, (__hip_bfloat16*)g1, pre2, pre3, N);
    agg_kernel<64, 0><<<ab, 256, 0, stream>>>(g1, dinv, row_off, col,
                                              b1, nullptr, nullptr, nullptr, x1, N);
    // --- layer 2 (+ x1@Ws13 fused)
    gemm_mfma1<<<(N + 127) / 128, 256, 0, stream>>>(
        x1, Wt1, bs13, dinv, (__hip_bfloat16*)g2, pre3, N);
    agg_kernel<32, 1><<<ab, 256, 0, stream>>>(g2, dinv, row_off, col,
                                              b2, pre2, nullptr, nullptr, x2, N);
    // --- layer 3 + output head
    gemm_mfma2<<<(N + 127) / 128, 256, 0, stream>>>(
        x2, Wt2, dinv, (__hip_bfloat16*)g3, N);
    agg_kernel<16, 2><<<ab, 256, 0, stream>>>(g3, dinv, row_off, col,
                                              b3, pre3, Wout, bout, d_out, N);
}